// Round 1
// baseline (1115.392 us; speedup 1.0000x reference)
//
#include <hip/hip_runtime.h>
#include <math.h>

// Problem constants (from reference): B=64, T=2048, D=256
#define BB 64
#define TT 2048
#define DD 256
#define DP 128            // D/2 -> float2 per thread
#define SS 64             // time segments
#define LL (TT / SS)      // 32 steps per segment

#define FLAG_EMPTY 0
#define FLAG_PARTIAL 1
#define FLAG_INCLUSIVE 2

// -------------------- math helpers --------------------

__device__ __forceinline__ float softplus_f(float x) {
    // stable log1p(exp(x)) to match jax.nn.softplus
    return (x > 0.f) ? (x + log1pf(expf(-x))) : log1pf(expf(x));
}

struct OUParams {
    float kx, ky;   // kappa
    float s2x, s2y; // sigma^2
    float rx, ry;   // sigma^2 / (2 kappa)  == stationary variance
    float mx, my;   // mu
};

__device__ __forceinline__ OUParams load_params(const float2* __restrict__ mu2,
                                                const float2* __restrict__ lk2,
                                                const float2* __restrict__ ls2,
                                                int tid) {
    float2 lk = lk2[tid], ls = ls2[tid], mu = mu2[tid];
    OUParams p;
    p.kx = softplus_f(lk.x) + 1e-6f;
    p.ky = softplus_f(lk.y) + 1e-6f;
    float sx = softplus_f(ls.x) + 1e-6f;
    float sy = softplus_f(ls.y) + 1e-6f;
    p.s2x = sx * sx;
    p.s2y = sy * sy;
    p.rx = p.s2x / fmaxf(2.f * p.kx, 1e-12f);
    p.ry = p.s2y / fmaxf(2.f * p.ky, 1e-12f);
    p.mx = mu.x;
    p.my = mu.y;
    return p;
}

// Exact OU transition coefficients for one component.
// A = exp(-kappa dt); Q via exact formula with Taylor fallback (matches ref).
__device__ __forceinline__ void ou_coeff(float dt, float kappa, float s2, float r,
                                         float mu, float& A, float& bm, float& sQ) {
    float e = kappa * dt;
    A = __expf(-e);
    float two = 2.f * e; // 2*kappa*dt
    float Qe = r * (1.f - A * A);
    float Qt = s2 * dt * fmaf(two * two, (1.f / 6.f), 1.f - e);
    float Q = (two < 1e-6f) ? Qt : Qe;
    sQ = sqrtf(Q);
    bm = mu * (1.f - A);
}

// -------------------- init: zero look-back flags (ws is re-poisoned) -------
__global__ void ou_init_flags(int* __restrict__ flags) {
    int i = blockIdx.x * blockDim.x + threadIdx.x;
    if (i < SS * BB) flags[i] = FLAG_EMPTY;
}

// -------------------- single-pass chained scan with decoupled look-back ----
// Block (s,b): stream noise segment ONCE, keep per-step innovation c[k] in
// registers, publish segment partial (P,U), look back for the segment-start
// state, publish inclusive, replay from registers, write output.
// blockIdx = s*BB + b  (s-major: look-back only waits on lower blockIdx).
__global__ __launch_bounds__(128, 3) void ou_lookback(
    const float* __restrict__ ts, const float2* __restrict__ noise2,
    const float2* __restrict__ mu2, const float2* __restrict__ lk2,
    const float2* __restrict__ ls2,
    float2* __restrict__ Pw, float2* __restrict__ Uw, float2* __restrict__ Yw,
    int* __restrict__ flags, float2* __restrict__ out2) {
    __shared__ float dts[LL];
    const int tid = threadIdx.x;
    const int s = blockIdx.x / BB;
    const int b = blockIdx.x % BB;
    const int t0 = s * LL;

    if (tid < LL) {
        int k = t0 + tid;
        float dt = 1e-6f;
        if (k >= 1) dt = fmaxf(ts[k] - ts[k - 1], 1e-6f);
        dts[tid] = dt;
    }
    __syncthreads();

    OUParams p = load_params(mu2, lk2, ls2, tid);
    const float2* np = noise2 + (size_t)b * TT * DP + tid;

    // ---- phase 1: stream noise once; build (P,U) and keep c[k] in regs ----
    float2 c[LL];                 // fully unrolled -> registers (64 VGPRs)
    float2 U = {0.f, 0.f};
    float2 P = {1.f, 1.f};
    float dtprev = -1.f;
    float Ax = 0.f, bmx = 0.f, sqx = 0.f, Ay = 0.f, bmy = 0.f, sqy = 0.f;
#pragma unroll
    for (int i = 0; i < LL; ++i) {
        float dt = dts[i];
        float2 n = np[(size_t)(t0 + i) * DP];
        if (dt != dtprev) {       // wave-uniform; ts is uniform -> ~1 eval
            ou_coeff(dt, p.kx, p.s2x, p.rx, p.mx, Ax, bmx, sqx);
            ou_coeff(dt, p.ky, p.s2y, p.ry, p.my, Ay, bmy, sqy);
            dtprev = dt;
        }
        float ax = Ax, ay = Ay;
        float2 cv;
        cv.x = fmaf(sqx, n.x, bmx);
        cv.y = fmaf(sqy, n.y, bmy);
        if (s == 0 && i == 0) {   // fold initial condition: y0 = mu + n*sqrt(var0)
            cv.x = fmaf(n.x, sqrtf(p.rx), p.mx);
            cv.y = fmaf(n.y, sqrtf(p.ry), p.my);
            ax = 0.f;
            ay = 0.f;             // absorbing: U becomes the actual state
        }
        c[i] = cv;
        U.x = fmaf(ax, U.x, cv.x);
        U.y = fmaf(ay, U.y, cv.y);
        P.x *= ax;
        P.y *= ay;
    }

    const int slot = s * BB + b;
    const size_t pidx = (size_t)slot * DP + tid;

    float2 ystart = {0.f, 0.f};
    if (s == 0) {
        // inclusive known immediately
        Yw[pidx] = U;
        __threadfence();
        __syncthreads();
        if (tid == 0)
            __hip_atomic_store(&flags[slot], FLAG_INCLUSIVE, __ATOMIC_RELEASE,
                               __HIP_MEMORY_SCOPE_AGENT);
    } else {
        if (s < SS - 1) {         // slot SS-1 is never read by anyone
            Pw[pidx] = P;
            Uw[pidx] = U;
            __threadfence();
            __syncthreads();
            if (tid == 0)
                __hip_atomic_store(&flags[slot], FLAG_PARTIAL, __ATOMIC_RELEASE,
                                   __HIP_MEMORY_SCOPE_AGENT);
        }
        // ---- decoupled look-back: fold partials, shortcut on inclusive ----
        float2 Pa = {1.f, 1.f}, Ua = {0.f, 0.f};
        int j = s - 1;
        for (;;) {
            const int js = j * BB + b;
            int f;
            while ((f = __hip_atomic_load(&flags[js], __ATOMIC_ACQUIRE,
                                          __HIP_MEMORY_SCOPE_AGENT)) == FLAG_EMPTY) {
                __builtin_amdgcn_s_sleep(1);
            }
            const size_t jidx = (size_t)js * DP + tid;
            if (f == FLAG_INCLUSIVE) {
                float2 Yj = Yw[jidx];
                ystart.x = fmaf(Pa.x, Yj.x, Ua.x);
                ystart.y = fmaf(Pa.y, Yj.y, Ua.y);
                break;
            }
            // partial: y_end(j) = Pj*y_end(j-1) + Uj -> fold into (Pa,Ua)
            float2 Pj = Pw[jidx];
            float2 Uj = Uw[jidx];
            Ua.x = fmaf(Pa.x, Uj.x, Ua.x);
            Ua.y = fmaf(Pa.y, Uj.y, Ua.y);
            Pa.x *= Pj.x;
            Pa.y *= Pj.y;
            --j;
        }
        if (s < SS - 1) {
            // publish inclusive ASAP to unblock successors
            float2 Yi;
            Yi.x = fmaf(P.x, ystart.x, U.x);
            Yi.y = fmaf(P.y, ystart.y, U.y);
            Yw[pidx] = Yi;
            __threadfence();
            __syncthreads();
            if (tid == 0)
                __hip_atomic_store(&flags[slot], FLAG_INCLUSIVE, __ATOMIC_RELEASE,
                                   __HIP_MEMORY_SCOPE_AGENT);
        }
    }

    // ---- replay from registers, write output (only output-write traffic) --
    float2* op = out2 + (size_t)b * TT * DP + tid;
    float2 y = ystart;            // s==0: ystart=0 and c[0] carries y0 (ax=0)
    dtprev = -1.f;
#pragma unroll
    for (int i = 0; i < LL; ++i) {
        float dt = dts[i];
        if (dt != dtprev) {
            Ax = __expf(-p.kx * dt);
            Ay = __expf(-p.ky * dt);
            dtprev = dt;
        }
        float ax = Ax, ay = Ay;
        if (s == 0 && i == 0) {
            ax = 0.f;
            ay = 0.f;
        }
        y.x = fmaf(ax, y.x, c[i].x);
        y.y = fmaf(ay, y.y, c[i].y);
        op[(size_t)(t0 + i) * DP] = y;
    }
}

// -------------------- fallback: plain per-chain scan (if ws too small) ------
__global__ __launch_bounds__(128) void ou_fallback(
    const float* __restrict__ ts, const float2* __restrict__ noise2,
    const float2* __restrict__ mu2, const float2* __restrict__ lk2,
    const float2* __restrict__ ls2, float2* __restrict__ out2) {
    __shared__ float dts[TT];
    const int tid = threadIdx.x;
    const int b = blockIdx.x;
    for (int i = tid; i < TT; i += 128) {
        float dt = 1e-6f;
        if (i >= 1) dt = fmaxf(ts[i] - ts[i - 1], 1e-6f);
        dts[i] = dt;
    }
    __syncthreads();

    OUParams p = load_params(mu2, lk2, ls2, tid);
    const float2* np = noise2 + (size_t)b * TT * DP + tid;
    float2* op = out2 + (size_t)b * TT * DP + tid;

    float2 n0 = np[0];
    float2 y;
    y.x = fmaf(n0.x, sqrtf(p.rx), p.mx);
    y.y = fmaf(n0.y, sqrtf(p.ry), p.my);
    op[0] = y;

#pragma unroll 4
    for (int k = 1; k < TT; ++k) {
        float dt = dts[k];
        float2 n = np[(size_t)k * DP];
        float Ax, bmx, sqx, Ay, bmy, sqy;
        ou_coeff(dt, p.kx, p.s2x, p.rx, p.mx, Ax, bmx, sqx);
        ou_coeff(dt, p.ky, p.s2y, p.ry, p.my, Ay, bmy, sqy);
        float cx = fmaf(sqx, n.x, bmx);
        float cy = fmaf(sqy, n.y, bmy);
        y.x = fmaf(Ax, y.x, cx);
        y.y = fmaf(Ay, y.y, cy);
        op[(size_t)k * DP] = y;
    }
}

// -------------------- launch --------------------
extern "C" void kernel_launch(void* const* d_in, const int* in_sizes, int n_in,
                              void* d_out, int out_size, void* d_ws, size_t ws_size,
                              hipStream_t stream) {
    const float* ts = (const float*)d_in[0];
    const float2* noise2 = (const float2*)d_in[1];
    const float2* mu2 = (const float2*)d_in[2];
    const float2* lk2 = (const float2*)d_in[3];
    const float2* ls2 = (const float2*)d_in[4];
    float2* out2 = (float2*)d_out;

    const size_t seg = (size_t)SS * BB * DP; // float2 elements per ws buffer
    const size_t need = 3 * seg * sizeof(float2) + (size_t)SS * BB * sizeof(int);
    if (ws_size >= need) {
        float2* Pw = (float2*)d_ws;
        float2* Uw = Pw + seg;
        float2* Yw = Uw + seg;
        int* flags = (int*)(Yw + seg);
        ou_init_flags<<<(SS * BB + 255) / 256, 256, 0, stream>>>(flags);
        ou_lookback<<<SS * BB, 128, 0, stream>>>(ts, noise2, mu2, lk2, ls2,
                                                 Pw, Uw, Yw, flags, out2);
    } else {
        ou_fallback<<<BB, 128, 0, stream>>>(ts, noise2, mu2, lk2, ls2, out2);
    }
}

// Round 4
// 90.519 us; speedup vs baseline: 12.3222x; 12.3222x over previous
//
#include <hip/hip_runtime.h>
#include <math.h>

// Problem constants (from reference): B=64, T=2048, D=256
#define BB 64
#define TT 2048
#define DD 256
#define D4 64             // D/4 -> one float4 per lane, one wave covers D
#define SS 64             // time segments
#define LL (TT / SS)      // 32 steps per segment
#define WPB 4             // waves per block (each wave owns one b, same s)
#define BPG (BB / WPB)    // b-groups per segment

// Native clang vector: elementwise ops, NT-store compatible.
typedef float f4 __attribute__((ext_vector_type(4)));

// -------------------- math helpers --------------------

__device__ __forceinline__ float softplus_f(float x) {
    // stable log1p(exp(x)) to match jax.nn.softplus
    return (x > 0.f) ? (x + log1pf(expf(-x))) : log1pf(expf(x));
}

struct P4 { f4 k, s2, r, mu; };   // per-lane params for 4 chains
struct C4 { f4 A, bm, sQ; };      // per-step coefficients for 4 chains
struct P1 { float k, s2, r; };    // scalar param triple
struct C1 { float A, bm, sQ; };   // scalar coeff triple

__device__ __forceinline__ P1 sp1(float lk, float ls) {
    P1 o;
    o.k = softplus_f(lk) + 1e-6f;
    float s = softplus_f(ls) + 1e-6f;
    o.s2 = s * s;
    o.r = o.s2 / fmaxf(2.f * o.k, 1e-12f);
    return o;
}

__device__ __forceinline__ P4 load_params4(const f4* __restrict__ mu4,
                                           const f4* __restrict__ lk4,
                                           const f4* __restrict__ ls4,
                                           int lane) {
    f4 lk = lk4[lane], ls = ls4[lane], mu = mu4[lane];
    P4 p;
    P1 a;
    a = sp1(lk.x, ls.x); p.k.x = a.k; p.s2.x = a.s2; p.r.x = a.r;
    a = sp1(lk.y, ls.y); p.k.y = a.k; p.s2.y = a.s2; p.r.y = a.r;
    a = sp1(lk.z, ls.z); p.k.z = a.k; p.s2.z = a.s2; p.r.z = a.r;
    a = sp1(lk.w, ls.w); p.k.w = a.k; p.s2.w = a.s2; p.r.w = a.r;
    p.mu = mu;
    return p;
}

// Exact OU transition coefficients for one component.
// A = exp(-kappa dt); Q via exact formula with Taylor fallback (matches ref).
__device__ __forceinline__ C1 ou_coeff(float dt, float kappa, float s2, float r,
                                       float mu) {
    C1 o;
    float e = kappa * dt;
    o.A = __expf(-e);
    float two = 2.f * e; // 2*kappa*dt
    float Qe = r * (1.f - o.A * o.A);
    float Qt = s2 * dt * fmaf(two * two, (1.f / 6.f), 1.f - e);
    float Q = (two < 1e-6f) ? Qt : Qe;
    o.sQ = sqrtf(Q);
    o.bm = mu * (1.f - o.A);
    return o;
}

__device__ __forceinline__ C4 coeff4(float dt, const P4& p) {
    C4 c;
    C1 o;
    o = ou_coeff(dt, p.k.x, p.s2.x, p.r.x, p.mu.x); c.A.x = o.A; c.bm.x = o.bm; c.sQ.x = o.sQ;
    o = ou_coeff(dt, p.k.y, p.s2.y, p.r.y, p.mu.y); c.A.y = o.A; c.bm.y = o.bm; c.sQ.y = o.sQ;
    o = ou_coeff(dt, p.k.z, p.s2.z, p.r.z, p.mu.z); c.A.z = o.A; c.bm.z = o.bm; c.sQ.z = o.sQ;
    o = ou_coeff(dt, p.k.w, p.s2.w, p.r.w, p.mu.w); c.A.w = o.A; c.bm.w = o.bm; c.sQ.w = o.sQ;
    return c;
}

// y = A*y + (sQ*n + bm) elementwise; fp-contract turns these into v_fma.
__device__ __forceinline__ void ou_step4(const C4& cc, const f4 n, f4& y) {
    f4 cv = cc.sQ * n + cc.bm;
    y = cc.A * y + cv;
}

__device__ __forceinline__ f4 sqrt4(const f4 v) {
    f4 r;
    r.x = sqrtf(v.x); r.y = sqrtf(v.y); r.z = sqrtf(v.z); r.w = sqrtf(v.w);
    return r;
}

// -------------------- pass 1: segment partials --------------------
// Wave w of block owns chain b = bg*WPB + w, segment s. Lane covers 4 chains.
// Segment 0 folds the initial condition directly into U (P = 0).
__global__ __launch_bounds__(256) void ou_pass1(
    const float* __restrict__ ts, const f4* __restrict__ noise4,
    const f4* __restrict__ mu4, const f4* __restrict__ lk4,
    const f4* __restrict__ ls4,
    f4* __restrict__ Pw, f4* __restrict__ Uw) {
    __shared__ float dts[LL];
    const int lane = threadIdx.x & 63;
    const int w = threadIdx.x >> 6;
    const int s = blockIdx.x / BPG;
    const int bg = blockIdx.x % BPG;
    const int b = bg * WPB + w;
    const int t0 = s * LL;

    if (threadIdx.x < LL) {
        int k = t0 + threadIdx.x;
        float dt = 1e-6f;
        if (k >= 1) dt = fmaxf(ts[k] - ts[k - 1], 1e-6f);
        dts[threadIdx.x] = dt;
    }
    __syncthreads();

    P4 p = load_params4(mu4, lk4, ls4, lane);
    const f4* np = noise4 + (size_t)b * TT * D4 + lane;

    f4 U = {0.f, 0.f, 0.f, 0.f};
    f4 P = {1.f, 1.f, 1.f, 1.f};
    int kstart = t0;
    if (s == 0) {
        f4 n0 = np[0];
        U = n0 * sqrt4(p.r) + p.mu;
        P = (f4){0.f, 0.f, 0.f, 0.f}; // absorbing: U is the actual state
        kstart = 1;
    }

    float dtprev = -1.f;
    C4 cc;
#pragma unroll 4
    for (int k = kstart; k < t0 + LL; ++k) {
        float dt = dts[k - t0];
        f4 n = np[(size_t)k * D4];
        if (dt != dtprev) { cc = coeff4(dt, p); dtprev = dt; } // wave-uniform
        ou_step4(cc, n, U);
        P *= cc.A;
    }

    size_t idx = ((size_t)s * BB + b) * D4 + lane;
    Pw[idx] = P;
    Uw[idx] = U;
}

// -------------------- pass 2: boundary scan over segments --------------------
__global__ __launch_bounds__(64) void ou_pass2(
    const f4* __restrict__ Pw, const f4* __restrict__ Uw,
    f4* __restrict__ Ys) {
    const int lane = threadIdx.x;
    const int b = blockIdx.x;
    const size_t stride = (size_t)BB * D4;
    const size_t i0 = (size_t)b * D4 + lane;

    f4 inc = Uw[i0]; // y at end of segment 0
#pragma unroll 8
    for (int s = 1; s < SS; ++s) {
        size_t idx = i0 + (size_t)s * stride;
        f4 Pv = Pw[idx];
        f4 Uv = Uw[idx];
        Ys[idx] = inc; // starting y for segment s (= y_{s*LL-1})
        inc = Pv * inc + Uv;
    }
}

// -------------------- pass 3: replay segments, write output --------------------
__global__ __launch_bounds__(256) void ou_pass3(
    const float* __restrict__ ts, const f4* __restrict__ noise4,
    const f4* __restrict__ mu4, const f4* __restrict__ lk4,
    const f4* __restrict__ ls4,
    const f4* __restrict__ Ys, f4* __restrict__ out4) {
    __shared__ float dts[LL];
    const int lane = threadIdx.x & 63;
    const int w = threadIdx.x >> 6;
    const int s = blockIdx.x / BPG;
    const int bg = blockIdx.x % BPG;
    const int b = bg * WPB + w;
    const int t0 = s * LL;

    if (threadIdx.x < LL) {
        int k = t0 + threadIdx.x;
        float dt = 1e-6f;
        if (k >= 1) dt = fmaxf(ts[k] - ts[k - 1], 1e-6f);
        dts[threadIdx.x] = dt;
    }
    __syncthreads();

    P4 p = load_params4(mu4, lk4, ls4, lane);
    const f4* np = noise4 + (size_t)b * TT * D4 + lane;
    f4* op = out4 + (size_t)b * TT * D4 + lane;

    f4 y;
    int kstart = t0;
    if (s == 0) {
        f4 n0 = np[0];
        y = n0 * sqrt4(p.r) + p.mu;
        __builtin_nontemporal_store(y, op);
        kstart = 1;
    } else {
        y = Ys[((size_t)s * BB + b) * D4 + lane];
    }

    float dtprev = -1.f;
    C4 cc;
#pragma unroll 4
    for (int k = kstart; k < t0 + LL; ++k) {
        float dt = dts[k - t0];
        f4 n = np[(size_t)k * D4];
        if (dt != dtprev) { cc = coeff4(dt, p); dtprev = dt; } // wave-uniform
        ou_step4(cc, n, y);
        // NT store: keep noise resident in L3 for this pass's own re-reads
        __builtin_nontemporal_store(y, op + (size_t)k * D4);
    }
}

// -------------------- fallback: plain per-chain scan (if ws too small) ------
__global__ __launch_bounds__(128) void ou_fallback(
    const float* __restrict__ ts, const float2* __restrict__ noise2,
    const float2* __restrict__ mu2, const float2* __restrict__ lk2,
    const float2* __restrict__ ls2, float2* __restrict__ out2) {
    __shared__ float dts[TT];
    const int tid = threadIdx.x;
    const int b = blockIdx.x;
    for (int i = tid; i < TT; i += 128) {
        float dt = 1e-6f;
        if (i >= 1) dt = fmaxf(ts[i] - ts[i - 1], 1e-6f);
        dts[i] = dt;
    }
    __syncthreads();

    float2 lk = lk2[tid], ls = ls2[tid], mu = mu2[tid];
    P1 px = sp1(lk.x, ls.x);
    P1 py = sp1(lk.y, ls.y);

    const float2* np = noise2 + (size_t)b * TT * 128 + tid;
    float2* op = out2 + (size_t)b * TT * 128 + tid;

    float2 n0 = np[0];
    float2 y;
    y.x = fmaf(n0.x, sqrtf(px.r), mu.x);
    y.y = fmaf(n0.y, sqrtf(py.r), mu.y);
    op[0] = y;

#pragma unroll 4
    for (int k = 1; k < TT; ++k) {
        float dt = dts[k];
        float2 n = np[(size_t)k * 128];
        C1 cx = ou_coeff(dt, px.k, px.s2, px.r, mu.x);
        C1 cy = ou_coeff(dt, py.k, py.s2, py.r, mu.y);
        y.x = fmaf(cx.A, y.x, fmaf(cx.sQ, n.x, cx.bm));
        y.y = fmaf(cy.A, y.y, fmaf(cy.sQ, n.y, cy.bm));
        op[(size_t)k * 128] = y;
    }
}

// -------------------- launch --------------------
extern "C" void kernel_launch(void* const* d_in, const int* in_sizes, int n_in,
                              void* d_out, int out_size, void* d_ws, size_t ws_size,
                              hipStream_t stream) {
    const float* ts = (const float*)d_in[0];
    const f4* noise4 = (const f4*)d_in[1];
    const f4* mu4 = (const f4*)d_in[2];
    const f4* lk4 = (const f4*)d_in[3];
    const f4* ls4 = (const f4*)d_in[4];
    f4* out4 = (f4*)d_out;

    const size_t seg = (size_t)SS * BB * D4; // f4 elements per ws buffer
    if (ws_size >= 3 * seg * sizeof(f4)) {
        f4* Pw = (f4*)d_ws;
        f4* Uw = Pw + seg;
        f4* Ys = Uw + seg;
        ou_pass1<<<SS * BPG, 256, 0, stream>>>(ts, noise4, mu4, lk4, ls4, Pw, Uw);
        ou_pass2<<<BB, 64, 0, stream>>>(Pw, Uw, Ys);
        ou_pass3<<<SS * BPG, 256, 0, stream>>>(ts, noise4, mu4, lk4, ls4, Ys, out4);
    } else {
        ou_fallback<<<BB, 128, 0, stream>>>(ts, (const float2*)d_in[1],
                                            (const float2*)d_in[2],
                                            (const float2*)d_in[3],
                                            (const float2*)d_in[4],
                                            (float2*)d_out);
    }
}

// Round 5
// 90.515 us; speedup vs baseline: 12.3227x; 1.0000x over previous
//
#include <hip/hip_runtime.h>
#include <hip/hip_cooperative_groups.h>
#include <math.h>

namespace cg = cooperative_groups;

// Problem constants (from reference): B=64, T=2048, D=256
#define BB 64
#define TT 2048
#define DD 256
#define D4 64             // D/4 -> one float4 per lane, one wave covers D
#define SS 64             // time segments
#define LL (TT / SS)      // 32 steps per segment
#define WPB 4             // waves per block (each wave owns one b, same s)
#define BPG (BB / WPB)    // b-groups per segment
#define GRID (SS * BPG)   // 1024 blocks -> 4 blocks/CU on 256 CUs
#define SCAN_BLOCKS ((BB * D4) / 256)  // 16 blocks cover all 4096 column-scans

// Native clang vector: elementwise ops, NT-store compatible.
typedef float f4 __attribute__((ext_vector_type(4)));

// -------------------- math helpers --------------------

__device__ __forceinline__ float softplus_f(float x) {
    // stable log1p(exp(x)) to match jax.nn.softplus
    return (x > 0.f) ? (x + log1pf(expf(-x))) : log1pf(expf(x));
}

struct P4 { f4 k, s2, r, mu; };   // per-lane params for 4 chains
struct C4 { f4 A, bm, sQ; };      // per-step coefficients for 4 chains
struct P1 { float k, s2, r; };    // scalar param triple
struct C1 { float A, bm, sQ; };   // scalar coeff triple

__device__ __forceinline__ P1 sp1(float lk, float ls) {
    P1 o;
    o.k = softplus_f(lk) + 1e-6f;
    float s = softplus_f(ls) + 1e-6f;
    o.s2 = s * s;
    o.r = o.s2 / fmaxf(2.f * o.k, 1e-12f);
    return o;
}

__device__ __forceinline__ P4 load_params4(const f4* __restrict__ mu4,
                                           const f4* __restrict__ lk4,
                                           const f4* __restrict__ ls4,
                                           int lane) {
    f4 lk = lk4[lane], ls = ls4[lane], mu = mu4[lane];
    P4 p;
    P1 a;
    a = sp1(lk.x, ls.x); p.k.x = a.k; p.s2.x = a.s2; p.r.x = a.r;
    a = sp1(lk.y, ls.y); p.k.y = a.k; p.s2.y = a.s2; p.r.y = a.r;
    a = sp1(lk.z, ls.z); p.k.z = a.k; p.s2.z = a.s2; p.r.z = a.r;
    a = sp1(lk.w, ls.w); p.k.w = a.k; p.s2.w = a.s2; p.r.w = a.r;
    p.mu = mu;
    return p;
}

// Exact OU transition coefficients for one component.
// A = exp(-kappa dt); Q via exact formula with Taylor fallback (matches ref).
__device__ __forceinline__ C1 ou_coeff(float dt, float kappa, float s2, float r,
                                       float mu) {
    C1 o;
    float e = kappa * dt;
    o.A = __expf(-e);
    float two = 2.f * e; // 2*kappa*dt
    float Qe = r * (1.f - o.A * o.A);
    float Qt = s2 * dt * fmaf(two * two, (1.f / 6.f), 1.f - e);
    float Q = (two < 1e-6f) ? Qt : Qe;
    o.sQ = sqrtf(Q);
    o.bm = mu * (1.f - o.A);
    return o;
}

__device__ __forceinline__ C4 coeff4(float dt, const P4& p) {
    C4 c;
    C1 o;
    o = ou_coeff(dt, p.k.x, p.s2.x, p.r.x, p.mu.x); c.A.x = o.A; c.bm.x = o.bm; c.sQ.x = o.sQ;
    o = ou_coeff(dt, p.k.y, p.s2.y, p.r.y, p.mu.y); c.A.y = o.A; c.bm.y = o.bm; c.sQ.y = o.sQ;
    o = ou_coeff(dt, p.k.z, p.s2.z, p.r.z, p.mu.z); c.A.z = o.A; c.bm.z = o.bm; c.sQ.z = o.sQ;
    o = ou_coeff(dt, p.k.w, p.s2.w, p.r.w, p.mu.w); c.A.w = o.A; c.bm.w = o.bm; c.sQ.w = o.sQ;
    return c;
}

// y = A*y + (sQ*n + bm) elementwise; fp-contract turns these into v_fma.
__device__ __forceinline__ void ou_step4(const C4& cc, const f4 n, f4& y) {
    f4 cv = cc.sQ * n + cc.bm;
    y = cc.A * y + cv;
}

__device__ __forceinline__ f4 sqrt4(const f4 v) {
    f4 r;
    r.x = sqrtf(v.x); r.y = sqrtf(v.y); r.z = sqrtf(v.z); r.w = sqrtf(v.w);
    return r;
}

// ==================== fused single-dispatch cooperative kernel ====================
// Phase 1: per-(s,b) tile partials (P,U).  grid.sync()
// Phase 2: 4096 independent column-scans over segment boundaries -> Ys. grid.sync()
// Phase 3: replay tiles from Ys, stream output with NT stores.
// Noise is read from HBM once (phase 1); phase 3's re-read hits L3 (134 MB < 256 MB,
// and output NT stores discourage L3 allocation).
__global__ __launch_bounds__(256, 4) void ou_fused(
    const float* __restrict__ ts, const f4* __restrict__ noise4,
    const f4* __restrict__ mu4, const f4* __restrict__ lk4,
    const f4* __restrict__ ls4,
    f4* __restrict__ Pw, f4* __restrict__ Uw, f4* __restrict__ Ys,
    f4* __restrict__ out4) {
    cg::grid_group grid = cg::this_grid();
    __shared__ float dts[LL];
    const int lane = threadIdx.x & 63;
    const int w = threadIdx.x >> 6;
    const int s = blockIdx.x / BPG;
    const int bg = blockIdx.x % BPG;
    const int b = bg * WPB + w;
    const int t0 = s * LL;

    if (threadIdx.x < LL) {
        int k = t0 + threadIdx.x;
        float dt = 1e-6f;
        if (k >= 1) dt = fmaxf(ts[k] - ts[k - 1], 1e-6f);
        dts[threadIdx.x] = dt;
    }
    __syncthreads();

    P4 p = load_params4(mu4, lk4, ls4, lane);
    const f4* np = noise4 + (size_t)b * TT * D4 + lane;
    const size_t myidx = ((size_t)s * BB + b) * D4 + lane;

    // ---------------- phase 1: segment partials ----------------
    {
        f4 U = {0.f, 0.f, 0.f, 0.f};
        f4 P = {1.f, 1.f, 1.f, 1.f};
        int kstart = t0;
        if (s == 0) {
            f4 n0 = np[0];
            U = n0 * sqrt4(p.r) + p.mu;
            P = (f4){0.f, 0.f, 0.f, 0.f}; // absorbing: U is the actual state
            kstart = 1;
        }
        float dtprev = -1.f;
        C4 cc;
#pragma unroll 4
        for (int k = kstart; k < t0 + LL; ++k) {
            float dt = dts[k - t0];
            f4 n = np[(size_t)k * D4];
            if (dt != dtprev) { cc = coeff4(dt, p); dtprev = dt; } // wave-uniform
            ou_step4(cc, n, U);
            P *= cc.A;
        }
        Pw[myidx] = P;
        Uw[myidx] = U;
    }

    grid.sync();

    // ---------------- phase 2: boundary scan (4096 independent columns) ----
    if (blockIdx.x < SCAN_BLOCKS) {
        const int gt = blockIdx.x * 256 + threadIdx.x; // 0..4095
        const int b2 = gt >> 6;
        const int l2 = gt & 63;
        const size_t stride = (size_t)BB * D4;
        const size_t i0 = (size_t)b2 * D4 + l2;
        f4 inc = Uw[i0]; // y at end of segment 0
#pragma unroll 8
        for (int s2 = 1; s2 < SS; ++s2) {
            size_t idx = i0 + (size_t)s2 * stride;
            f4 Pv = Pw[idx];
            f4 Uv = Uw[idx];
            Ys[idx] = inc; // starting y for segment s2 (= y_{s2*LL-1})
            inc = Pv * inc + Uv;
        }
    }

    grid.sync();

    // ---------------- phase 3: replay, write output ----------------
    {
        f4* op = out4 + (size_t)b * TT * D4 + lane;
        f4 y;
        int kstart = t0;
        if (s == 0) {
            f4 n0 = np[0];
            y = n0 * sqrt4(p.r) + p.mu;
            __builtin_nontemporal_store(y, op);
            kstart = 1;
        } else {
            y = Ys[myidx];
        }
        float dtprev = -1.f;
        C4 cc;
#pragma unroll 4
        for (int k = kstart; k < t0 + LL; ++k) {
            float dt = dts[k - t0];
            f4 n = np[(size_t)k * D4];
            if (dt != dtprev) { cc = coeff4(dt, p); dtprev = dt; } // wave-uniform
            ou_step4(cc, n, y);
            __builtin_nontemporal_store(y, op + (size_t)k * D4);
        }
    }
}

// ==================== fallback: proven 3-pass version ====================

__global__ __launch_bounds__(256) void ou_pass1(
    const float* __restrict__ ts, const f4* __restrict__ noise4,
    const f4* __restrict__ mu4, const f4* __restrict__ lk4,
    const f4* __restrict__ ls4,
    f4* __restrict__ Pw, f4* __restrict__ Uw) {
    __shared__ float dts[LL];
    const int lane = threadIdx.x & 63;
    const int w = threadIdx.x >> 6;
    const int s = blockIdx.x / BPG;
    const int bg = blockIdx.x % BPG;
    const int b = bg * WPB + w;
    const int t0 = s * LL;

    if (threadIdx.x < LL) {
        int k = t0 + threadIdx.x;
        float dt = 1e-6f;
        if (k >= 1) dt = fmaxf(ts[k] - ts[k - 1], 1e-6f);
        dts[threadIdx.x] = dt;
    }
    __syncthreads();

    P4 p = load_params4(mu4, lk4, ls4, lane);
    const f4* np = noise4 + (size_t)b * TT * D4 + lane;

    f4 U = {0.f, 0.f, 0.f, 0.f};
    f4 P = {1.f, 1.f, 1.f, 1.f};
    int kstart = t0;
    if (s == 0) {
        f4 n0 = np[0];
        U = n0 * sqrt4(p.r) + p.mu;
        P = (f4){0.f, 0.f, 0.f, 0.f};
        kstart = 1;
    }

    float dtprev = -1.f;
    C4 cc;
#pragma unroll 4
    for (int k = kstart; k < t0 + LL; ++k) {
        float dt = dts[k - t0];
        f4 n = np[(size_t)k * D4];
        if (dt != dtprev) { cc = coeff4(dt, p); dtprev = dt; }
        ou_step4(cc, n, U);
        P *= cc.A;
    }

    size_t idx = ((size_t)s * BB + b) * D4 + lane;
    Pw[idx] = P;
    Uw[idx] = U;
}

__global__ __launch_bounds__(64) void ou_pass2(
    const f4* __restrict__ Pw, const f4* __restrict__ Uw,
    f4* __restrict__ Ys) {
    const int lane = threadIdx.x;
    const int b = blockIdx.x;
    const size_t stride = (size_t)BB * D4;
    const size_t i0 = (size_t)b * D4 + lane;

    f4 inc = Uw[i0];
#pragma unroll 8
    for (int s = 1; s < SS; ++s) {
        size_t idx = i0 + (size_t)s * stride;
        f4 Pv = Pw[idx];
        f4 Uv = Uw[idx];
        Ys[idx] = inc;
        inc = Pv * inc + Uv;
    }
}

__global__ __launch_bounds__(256) void ou_pass3(
    const float* __restrict__ ts, const f4* __restrict__ noise4,
    const f4* __restrict__ mu4, const f4* __restrict__ lk4,
    const f4* __restrict__ ls4,
    const f4* __restrict__ Ys, f4* __restrict__ out4) {
    __shared__ float dts[LL];
    const int lane = threadIdx.x & 63;
    const int w = threadIdx.x >> 6;
    const int s = blockIdx.x / BPG;
    const int bg = blockIdx.x % BPG;
    const int b = bg * WPB + w;
    const int t0 = s * LL;

    if (threadIdx.x < LL) {
        int k = t0 + threadIdx.x;
        float dt = 1e-6f;
        if (k >= 1) dt = fmaxf(ts[k] - ts[k - 1], 1e-6f);
        dts[threadIdx.x] = dt;
    }
    __syncthreads();

    P4 p = load_params4(mu4, lk4, ls4, lane);
    const f4* np = noise4 + (size_t)b * TT * D4 + lane;
    f4* op = out4 + (size_t)b * TT * D4 + lane;

    f4 y;
    int kstart = t0;
    if (s == 0) {
        f4 n0 = np[0];
        y = n0 * sqrt4(p.r) + p.mu;
        __builtin_nontemporal_store(y, op);
        kstart = 1;
    } else {
        y = Ys[((size_t)s * BB + b) * D4 + lane];
    }

    float dtprev = -1.f;
    C4 cc;
#pragma unroll 4
    for (int k = kstart; k < t0 + LL; ++k) {
        float dt = dts[k - t0];
        f4 n = np[(size_t)k * D4];
        if (dt != dtprev) { cc = coeff4(dt, p); dtprev = dt; }
        ou_step4(cc, n, y);
        __builtin_nontemporal_store(y, op + (size_t)k * D4);
    }
}

// -------------------- last-resort fallback: plain per-chain scan ------------
__global__ __launch_bounds__(128) void ou_fallback(
    const float* __restrict__ ts, const float2* __restrict__ noise2,
    const float2* __restrict__ mu2, const float2* __restrict__ lk2,
    const float2* __restrict__ ls2, float2* __restrict__ out2) {
    __shared__ float dts[TT];
    const int tid = threadIdx.x;
    const int b = blockIdx.x;
    for (int i = tid; i < TT; i += 128) {
        float dt = 1e-6f;
        if (i >= 1) dt = fmaxf(ts[i] - ts[i - 1], 1e-6f);
        dts[i] = dt;
    }
    __syncthreads();

    float2 lk = lk2[tid], ls = ls2[tid], mu = mu2[tid];
    P1 px = sp1(lk.x, ls.x);
    P1 py = sp1(lk.y, ls.y);

    const float2* np = noise2 + (size_t)b * TT * 128 + tid;
    float2* op = out2 + (size_t)b * TT * 128 + tid;

    float2 n0 = np[0];
    float2 y;
    y.x = fmaf(n0.x, sqrtf(px.r), mu.x);
    y.y = fmaf(n0.y, sqrtf(py.r), mu.y);
    op[0] = y;

#pragma unroll 4
    for (int k = 1; k < TT; ++k) {
        float dt = dts[k];
        float2 n = np[(size_t)k * 128];
        C1 cx = ou_coeff(dt, px.k, px.s2, px.r, mu.x);
        C1 cy = ou_coeff(dt, py.k, py.s2, py.r, mu.y);
        y.x = fmaf(cx.A, y.x, fmaf(cx.sQ, n.x, cx.bm));
        y.y = fmaf(cy.A, y.y, fmaf(cy.sQ, n.y, cy.bm));
        op[(size_t)k * 128] = y;
    }
}

// -------------------- launch --------------------
extern "C" void kernel_launch(void* const* d_in, const int* in_sizes, int n_in,
                              void* d_out, int out_size, void* d_ws, size_t ws_size,
                              hipStream_t stream) {
    const float* ts = (const float*)d_in[0];
    const f4* noise4 = (const f4*)d_in[1];
    const f4* mu4 = (const f4*)d_in[2];
    const f4* lk4 = (const f4*)d_in[3];
    const f4* ls4 = (const f4*)d_in[4];
    f4* out4 = (f4*)d_out;

    const size_t seg = (size_t)SS * BB * D4; // f4 elements per ws buffer
    const bool have_ws = ws_size >= 3 * seg * sizeof(f4);

    if (have_ws) {
        f4* Pw = (f4*)d_ws;
        f4* Uw = Pw + seg;
        f4* Ys = Uw + seg;

        // one-time check: can all GRID blocks be co-resident for cooperative launch?
        static int coop_ok = -1;
        if (coop_ok < 0) {
            int nb = 0, ncu = 0, dev = 0;
            hipError_t e1 = hipGetDevice(&dev);
            hipError_t e2 = hipOccupancyMaxActiveBlocksPerMultiprocessor(
                &nb, reinterpret_cast<const void*>(&ou_fused), 256, 0);
            hipError_t e3 = hipDeviceGetAttribute(
                &ncu, hipDeviceAttributeMultiprocessorCount, dev);
            coop_ok = (e1 == hipSuccess && e2 == hipSuccess && e3 == hipSuccess &&
                       (long)nb * ncu >= GRID) ? 1 : 0;
        }

        if (coop_ok) {
            void* args[] = {(void*)&ts, (void*)&noise4, (void*)&mu4, (void*)&lk4,
                            (void*)&ls4, (void*)&Pw, (void*)&Uw, (void*)&Ys,
                            (void*)&out4};
            hipError_t le = hipLaunchCooperativeKernel(
                reinterpret_cast<const void*>(&ou_fused), dim3(GRID), dim3(256),
                args, 0, stream);
            if (le == hipSuccess) return;
            (void)hipGetLastError(); // clear; fall through to 3-pass
        }

        ou_pass1<<<GRID, 256, 0, stream>>>(ts, noise4, mu4, lk4, ls4, Pw, Uw);
        ou_pass2<<<BB, 64, 0, stream>>>(Pw, Uw, Ys);
        ou_pass3<<<GRID, 256, 0, stream>>>(ts, noise4, mu4, lk4, ls4, Ys, out4);
    } else {
        ou_fallback<<<BB, 128, 0, stream>>>(ts, (const float2*)d_in[1],
                                            (const float2*)d_in[2],
                                            (const float2*)d_in[3],
                                            (const float2*)d_in[4],
                                            (float2*)d_out);
    }
}

// Round 6
// 88.862 us; speedup vs baseline: 12.5520x; 1.0186x over previous
//
#include <hip/hip_runtime.h>
#include <math.h>

// Problem constants (from reference): B=64, T=2048, D=256
#define BB 64
#define TT 2048
#define DD 256
#define D4 64             // D/4 -> one float4 per lane, one wave covers D
#define SS 64             // time segments
#define LL (TT / SS)      // 32 steps per segment
#define WPB 4             // waves per block (each wave owns one b, same s)
#define BPG (BB / WPB)    // b-groups per segment
#define GRID (SS * BPG)   // 1024 blocks -> 4 blocks/CU on 256 CUs

// Native clang vector: elementwise ops, NT-store compatible.
typedef float f4 __attribute__((ext_vector_type(4)));

// -------------------- math helpers --------------------

__device__ __forceinline__ float softplus_f(float x) {
    // stable log1p(exp(x)) to match jax.nn.softplus
    return (x > 0.f) ? (x + log1pf(expf(-x))) : log1pf(expf(x));
}

struct P4 { f4 k, s2, r, mu; };   // per-lane params for 4 chains
struct C4 { f4 A, bm, sQ; };      // per-step coefficients for 4 chains
struct P1 { float k, s2, r; };    // scalar param triple
struct C1 { float A, bm, sQ; };   // scalar coeff triple

__device__ __forceinline__ P1 sp1(float lk, float ls) {
    P1 o;
    o.k = softplus_f(lk) + 1e-6f;
    float s = softplus_f(ls) + 1e-6f;
    o.s2 = s * s;
    o.r = o.s2 / fmaxf(2.f * o.k, 1e-12f);
    return o;
}

__device__ __forceinline__ P4 load_params4(const f4* __restrict__ mu4,
                                           const f4* __restrict__ lk4,
                                           const f4* __restrict__ ls4,
                                           int lane) {
    f4 lk = lk4[lane], ls = ls4[lane], mu = mu4[lane];
    P4 p;
    P1 a;
    a = sp1(lk.x, ls.x); p.k.x = a.k; p.s2.x = a.s2; p.r.x = a.r;
    a = sp1(lk.y, ls.y); p.k.y = a.k; p.s2.y = a.s2; p.r.y = a.r;
    a = sp1(lk.z, ls.z); p.k.z = a.k; p.s2.z = a.s2; p.r.z = a.r;
    a = sp1(lk.w, ls.w); p.k.w = a.k; p.s2.w = a.s2; p.r.w = a.r;
    p.mu = mu;
    return p;
}

// Exact OU transition coefficients for one component.
// A = exp(-kappa dt); Q via exact formula with Taylor fallback (matches ref).
__device__ __forceinline__ C1 ou_coeff(float dt, float kappa, float s2, float r,
                                       float mu) {
    C1 o;
    float e = kappa * dt;
    o.A = __expf(-e);
    float two = 2.f * e; // 2*kappa*dt
    float Qe = r * (1.f - o.A * o.A);
    float Qt = s2 * dt * fmaf(two * two, (1.f / 6.f), 1.f - e);
    float Q = (two < 1e-6f) ? Qt : Qe;
    o.sQ = sqrtf(Q);
    o.bm = mu * (1.f - o.A);
    return o;
}

__device__ __forceinline__ C4 coeff4(float dt, const P4& p) {
    C4 c;
    C1 o;
    o = ou_coeff(dt, p.k.x, p.s2.x, p.r.x, p.mu.x); c.A.x = o.A; c.bm.x = o.bm; c.sQ.x = o.sQ;
    o = ou_coeff(dt, p.k.y, p.s2.y, p.r.y, p.mu.y); c.A.y = o.A; c.bm.y = o.bm; c.sQ.y = o.sQ;
    o = ou_coeff(dt, p.k.z, p.s2.z, p.r.z, p.mu.z); c.A.z = o.A; c.bm.z = o.bm; c.sQ.z = o.sQ;
    o = ou_coeff(dt, p.k.w, p.s2.w, p.r.w, p.mu.w); c.A.w = o.A; c.bm.w = o.bm; c.sQ.w = o.sQ;
    return c;
}

// y = A*y + (sQ*n + bm) elementwise; fp-contract turns these into v_fma.
__device__ __forceinline__ void ou_step4(const C4& cc, const f4 n, f4& y) {
    f4 cv = cc.sQ * n + cc.bm;
    y = cc.A * y + cv;
}

__device__ __forceinline__ f4 sqrt4(const f4 v) {
    f4 r;
    r.x = sqrtf(v.x); r.y = sqrtf(v.y); r.z = sqrtf(v.z); r.w = sqrtf(v.w);
    return r;
}

// -------------------- kernel A: segment partials --------------------
// Wave w of block owns chain b = bg*WPB + w, segment s. Lane covers 4 chains.
// Reads noise ONCE from HBM (populating L3), writes 8.4 MB of (P,U).
// Segment 0 folds the initial condition directly into U (P = 0).
__global__ __launch_bounds__(256) void ou_partials(
    const float* __restrict__ ts, const f4* __restrict__ noise4,
    const f4* __restrict__ mu4, const f4* __restrict__ lk4,
    const f4* __restrict__ ls4,
    f4* __restrict__ Pw, f4* __restrict__ Uw) {
    __shared__ float dts[LL];
    const int lane = threadIdx.x & 63;
    const int w = threadIdx.x >> 6;
    const int s = blockIdx.x / BPG;
    const int bg = blockIdx.x % BPG;
    const int b = bg * WPB + w;
    const int t0 = s * LL;

    if (threadIdx.x < LL) {
        int k = t0 + threadIdx.x;
        float dt = 1e-6f;
        if (k >= 1) dt = fmaxf(ts[k] - ts[k - 1], 1e-6f);
        dts[threadIdx.x] = dt;
    }
    __syncthreads();

    P4 p = load_params4(mu4, lk4, ls4, lane);
    const f4* np = noise4 + (size_t)b * TT * D4 + lane;

    f4 U = {0.f, 0.f, 0.f, 0.f};
    f4 P = {1.f, 1.f, 1.f, 1.f};
    int kstart = t0;
    if (s == 0) {
        f4 n0 = np[0];
        U = n0 * sqrt4(p.r) + p.mu;
        P = (f4){0.f, 0.f, 0.f, 0.f}; // absorbing: U is the actual state
        kstart = 1;
    }

    float dtprev = -1.f;
    C4 cc;
#pragma unroll 4
    for (int k = kstart; k < t0 + LL; ++k) {
        float dt = dts[k - t0];
        f4 n = np[(size_t)k * D4];
        if (dt != dtprev) { cc = coeff4(dt, p); dtprev = dt; } // wave-uniform
        ou_step4(cc, n, U);
        P *= cc.A;
    }

    size_t idx = ((size_t)s * BB + b) * D4 + lane;
    Pw[idx] = P;  // regular stores: keep partials L2/L3-resident for kernel B
    Uw[idx] = U;
}

// -------------------- kernel B: per-block boundary scan + replay -----------
// Each block (s,b) computes its own segment-start state by scanning the
// L2/L3-resident partials of segments 0..s-1 (<=63 dependent f4-fmas; no
// cross-block sync of any kind), then replays its segment reading noise
// (L3-resident from kernel A) and NT-stores the output.
// Long scans get LOW blockIdx so they dispatch first.
__global__ __launch_bounds__(256) void ou_scan_replay(
    const float* __restrict__ ts, const f4* __restrict__ noise4,
    const f4* __restrict__ mu4, const f4* __restrict__ lk4,
    const f4* __restrict__ ls4,
    const f4* __restrict__ Pw, const f4* __restrict__ Uw,
    f4* __restrict__ out4) {
    __shared__ float dts[LL];
    const int lane = threadIdx.x & 63;
    const int w = threadIdx.x >> 6;
    const int s = (SS - 1) - (blockIdx.x / BPG);  // reversed: long scans first
    const int bg = blockIdx.x % BPG;
    const int b = bg * WPB + w;
    const int t0 = s * LL;

    if (threadIdx.x < LL) {
        int k = t0 + threadIdx.x;
        float dt = 1e-6f;
        if (k >= 1) dt = fmaxf(ts[k] - ts[k - 1], 1e-6f);
        dts[threadIdx.x] = dt;
    }
    __syncthreads();

    P4 p = load_params4(mu4, lk4, ls4, lane);
    const f4* np = noise4 + (size_t)b * TT * D4 + lane;
    f4* op = out4 + (size_t)b * TT * D4 + lane;

    f4 y;
    int kstart = t0;
    if (s == 0) {
        f4 n0 = np[0];
        y = n0 * sqrt4(p.r) + p.mu;
        __builtin_nontemporal_store(y, op);
        kstart = 1;
    } else {
        // boundary scan over segments 0..s-1 for this (b, lane) column.
        // Segment 0's (P,U) is absorbing (P=0, U=y_end), so inc starts at U_0.
        const size_t stride = (size_t)BB * D4;
        const size_t i0 = (size_t)b * D4 + lane;
        f4 inc = Uw[i0];
#pragma unroll 4
        for (int j = 1; j < s; ++j) {
            size_t idx = i0 + (size_t)j * stride;
            f4 Pv = Pw[idx];
            f4 Uv = Uw[idx];
            inc = Pv * inc + Uv;
        }
        y = inc; // y at end of segment s-1 == start state for segment s
    }

    float dtprev = -1.f;
    C4 cc;
#pragma unroll 4
    for (int k = kstart; k < t0 + LL; ++k) {
        float dt = dts[k - t0];
        f4 n = np[(size_t)k * D4];
        if (dt != dtprev) { cc = coeff4(dt, p); dtprev = dt; } // wave-uniform
        ou_step4(cc, n, y);
        // NT store: don't let the out-stream evict noise from L3
        __builtin_nontemporal_store(y, op + (size_t)k * D4);
    }
}

// -------------------- last-resort fallback: plain per-chain scan ------------
__global__ __launch_bounds__(128) void ou_fallback(
    const float* __restrict__ ts, const float2* __restrict__ noise2,
    const float2* __restrict__ mu2, const float2* __restrict__ lk2,
    const float2* __restrict__ ls2, float2* __restrict__ out2) {
    __shared__ float dts[TT];
    const int tid = threadIdx.x;
    const int b = blockIdx.x;
    for (int i = tid; i < TT; i += 128) {
        float dt = 1e-6f;
        if (i >= 1) dt = fmaxf(ts[i] - ts[i - 1], 1e-6f);
        dts[i] = dt;
    }
    __syncthreads();

    float2 lk = lk2[tid], ls = ls2[tid], mu = mu2[tid];
    P1 px = sp1(lk.x, ls.x);
    P1 py = sp1(lk.y, ls.y);

    const float2* np = noise2 + (size_t)b * TT * 128 + tid;
    float2* op = out2 + (size_t)b * TT * 128 + tid;

    float2 n0 = np[0];
    float2 y;
    y.x = fmaf(n0.x, sqrtf(px.r), mu.x);
    y.y = fmaf(n0.y, sqrtf(py.r), mu.y);
    op[0] = y;

#pragma unroll 4
    for (int k = 1; k < TT; ++k) {
        float dt = dts[k];
        float2 n = np[(size_t)k * 128];
        C1 cx = ou_coeff(dt, px.k, px.s2, px.r, mu.x);
        C1 cy = ou_coeff(dt, py.k, py.s2, py.r, mu.y);
        y.x = fmaf(cx.A, y.x, fmaf(cx.sQ, n.x, cx.bm));
        y.y = fmaf(cy.A, y.y, fmaf(cy.sQ, n.y, cy.bm));
        op[(size_t)k * 128] = y;
    }
}

// -------------------- launch --------------------
extern "C" void kernel_launch(void* const* d_in, const int* in_sizes, int n_in,
                              void* d_out, int out_size, void* d_ws, size_t ws_size,
                              hipStream_t stream) {
    const float* ts = (const float*)d_in[0];
    const f4* noise4 = (const f4*)d_in[1];
    const f4* mu4 = (const f4*)d_in[2];
    const f4* lk4 = (const f4*)d_in[3];
    const f4* ls4 = (const f4*)d_in[4];
    f4* out4 = (f4*)d_out;

    const size_t seg = (size_t)SS * BB * D4; // f4 elements per ws buffer
    if (ws_size >= 2 * seg * sizeof(f4)) {
        f4* Pw = (f4*)d_ws;
        f4* Uw = Pw + seg;
        ou_partials<<<GRID, 256, 0, stream>>>(ts, noise4, mu4, lk4, ls4, Pw, Uw);
        ou_scan_replay<<<GRID, 256, 0, stream>>>(ts, noise4, mu4, lk4, ls4,
                                                 Pw, Uw, out4);
    } else {
        ou_fallback<<<BB, 128, 0, stream>>>(ts, (const float2*)d_in[1],
                                            (const float2*)d_in[2],
                                            (const float2*)d_in[3],
                                            (const float2*)d_in[4],
                                            (float2*)d_out);
    }
}